// Round 7
// baseline (122.648 us; speedup 1.0000x reference)
//
#include <hip/hip_runtime.h>
#include <hip/hip_bf16.h>
#include <math.h>

#define B_   16
#define N_   32
#define I_   1152
#define DIN  16
#define D_   64
#define TI   8             // i's per k_xhat block
#define IB   (I_/TI)       // 144 i-tiles
#define IC   16            // i-chunks in routing (72 i each)
#define BND  (B_*N_*D_)    // 32768

#if __has_builtin(__builtin_amdgcn_exp2f)
#define EXP2(x) __builtin_amdgcn_exp2f(x)
#else
#define EXP2(x) exp2f(x)
#endif

#define LOG2E 1.4426950408889634f

typedef __attribute__((ext_vector_type(8))) short short8v;
typedef __attribute__((ext_vector_type(4))) float f32x4;

__device__ __forceinline__ float squash1(float s) {
    float sq = s * s;
    return (sq / (1.0f + sq)) * s * rsqrtf(sq + 1e-9f);
}
__device__ __forceinline__ unsigned short bfh(float v) {
    return __builtin_bit_cast(unsigned short, __float2bfloat16(v));
}
__device__ __forceinline__ float bff(unsigned short u) {
    unsigned int x = ((unsigned int)u) << 16;
    return __builtin_bit_cast(float, x);
}

// K1: x_hat via MFMA (R5 engine), with NON-TEMPORAL W loads.
// W is streamed exactly once per replay with zero reuse; letting it allocate
// in the 256MB L3 thrashed the cache (FETCH ~ W/2 every replay, ~3 TB/s
// L3-allocation ceiling = the R1-R5 invariant 93us). nt loads keep W out of
// L3 so xh/part stay resident for the routing passes.
// Per (n,i): C[64d x 16b] = W[64d x 16k] * inp[16k x 16b], one
// mfma_f32_16x16x32_bf16 per (wave m-tile, i); K-slots 0..15 = W_hi bf16,
// 16..31 = W_lo residual, inputs duplicated -> fp32-grade W precision.
// C-frag: col=lane&15=b, row(d)=(lane>>4)*4+reg. xh2 layout [n][i][d][b].
__global__ __launch_bounds__(256) void k_xhat(const float* __restrict__ inp,
                                              const float* __restrict__ W,
                                              unsigned short* __restrict__ xh2,
                                              float* __restrict__ part) {
    const int bx = blockIdx.x;
    const int n  = bx / IB;
    const int ib = bx % IB;
    const int i0 = ib * TI;
    const int t  = threadIdx.x;
    const int l  = t & 63;
    const int mt = t >> 6;                 // wave id = d m-tile (0..3)
    const int row   = l & 15;              // A: d-in-tile  | B: b
    const int koctA = (l >> 4) & 1;        // k-octet within K=16 (lanes 32+ mirror)
    const bool loHalf = (l >= 32);         // these lanes supply W_lo

    const float* wbase = W + ((size_t)(n * I_ + i0) * 64 + mt * 16 + row) * 16 + koctA * 8;
    const float* ibase = inp + (size_t)row * (I_ * DIN) + (size_t)i0 * 16 + koctA * 8;

    f32x4 acc[TI];
    #pragma unroll
    for (int i = 0; i < TI; ++i) acc[i] = (f32x4){0.f, 0.f, 0.f, 0.f};

    #pragma unroll
    for (int i = 0; i < TI; ++i) {
        const f32x4* wp = (const f32x4*)(wbase + (size_t)i * 1024);
        const f32x4* xp = (const f32x4*)(ibase + (size_t)i * 16);
        f32x4 w0 = __builtin_nontemporal_load(wp);
        f32x4 w1 = __builtin_nontemporal_load(wp + 1);
        f32x4 x0 = xp[0], x1 = xp[1];
        float wv[8] = {w0.x, w0.y, w0.z, w0.w, w1.x, w1.y, w1.z, w1.w};
        float xv[8] = {x0.x, x0.y, x0.z, x0.w, x1.x, x1.y, x1.z, x1.w};
        short8v af, bf;
        #pragma unroll
        for (int j = 0; j < 8; ++j) {
            unsigned short hi = bfh(wv[j]);
            unsigned short lo = bfh(wv[j] - bff(hi));   // exact residual, then RNE
            af[j] = (short)(loHalf ? lo : hi);
            bf[j] = (short)bfh(xv[j]);
        }
        acc[i] = __builtin_amdgcn_mfma_f32_16x16x32_bf16(af, bf, acc[i], 0, 0, 0);
    }

    // store x_hat bf16, layout [n][i][d][b]
    #pragma unroll
    for (int i = 0; i < TI; ++i) {
        size_t rb = ((size_t)(n * I_ + i0 + i) * 64 + mt * 16 + (l >> 4) * 4) * 16 + (l & 15);
        #pragma unroll
        for (int r = 0; r < 4; ++r) xh2[rb + (size_t)r * 16] = bfh(acc[i][r]);
    }

    // s0 partial: sum over this block's 8 i's -> part[ib][b][n][d] (fp32)
    f32x4 s0v = acc[0];
    #pragma unroll
    for (int i = 1; i < TI; ++i) s0v += acc[i];
    size_t pidx = (((size_t)ib * B_ + (l & 15)) * N_ + n) * 64 + mt * 16 + (l >> 4) * 4;
    *(f32x4*)(part + pidx) = s0v;
}

// K2: coef = squash(mean over i of x_hat) — routing iteration 0.
__global__ __launch_bounds__(256) void k_out0(const float* __restrict__ part,
                                              float* __restrict__ coef) {
    const int t = blockIdx.x * 256 + threadIdx.x;   // (b,n,d) packed = coef index
    float s = 0.0f;
    for (int j = 0; j < IB; ++j) s += part[(size_t)j * BND + t];
    s *= (1.0f / (float)I_);
    coef[t] = squash1(s);
}

// K3: routing partial pass over xh2[n][i][d][b]. No max-tracking needed:
// |x|<~25, |coef|<=2 => |logit|<=50, exp2 safe in fp32. Accumulate z=sum(e),
// a=sum(e*x) per (d,b) over 72 i's. part2[ic][n][d][b][2] = {z,a}.
// grid = N_*IC blocks, 256 threads; thread t: d=t>>2, b=(t&3)*4+j (4 b's).
__global__ __launch_bounds__(256) void k_rpart(const unsigned short* __restrict__ xh2,
                                               const float* __restrict__ coef,
                                               float* __restrict__ part2) {
    const int bx = blockIdx.x;
    const int n  = bx >> 4;
    const int ic = bx & 15;
    const int t  = threadIdx.x;
    const int d  = t >> 2;
    const int bq = t & 3;

    const unsigned short* base = xh2 + ((size_t)n * I_ + (size_t)ic * (I_ / IC)) * 1024
                               + (size_t)d * 16 + bq * 4;
    float c2[4], z[4] = {0, 0, 0, 0}, a[4] = {0, 0, 0, 0};
    #pragma unroll
    for (int j = 0; j < 4; ++j) c2[j] = coef[((bq * 4 + j) * N_ + n) * D_ + d] * LOG2E;

    #pragma unroll 4
    for (int i = 0; i < I_ / IC; ++i) {
        const unsigned int* p = (const unsigned int*)(base + (size_t)i * 1024);
        unsigned int u0 = p[0], u1 = p[1];
        unsigned short s4[4] = {(unsigned short)(u0 & 0xffffu), (unsigned short)(u0 >> 16),
                                (unsigned short)(u1 & 0xffffu), (unsigned short)(u1 >> 16)};
        #pragma unroll
        for (int j = 0; j < 4; ++j) {
            float x = bff(s4[j]);
            float e = EXP2(x * c2[j]);
            z[j] += e;
            a[j] = fmaf(e, x, a[j]);
        }
    }

    // part2[ic][n][d][b][2], thread owns b = bq*4..bq*4+3 -> 8 contiguous floats
    size_t pidx = ((((size_t)ic * N_ + n) * 64 + d) * 16 + bq * 4) * 2;
    f32x4 v0 = {z[0], a[0], z[1], a[1]};
    f32x4 v1 = {z[2], a[2], z[3], a[3]};
    *(f32x4*)(part2 + pidx)     = v0;
    *(f32x4*)(part2 + pidx + 4) = v1;
}

// K4: routing finisher. gid packs (n,d,b) = part2's inner index order.
// final=0: coef += squash(a/z). final=1: out[b][n][d] = squash(a/z).
__global__ __launch_bounds__(256) void k_rfin(const float* __restrict__ part2,
                                              const float* __restrict__ coefIn,
                                              float* __restrict__ outp,
                                              int final_) {
    const int gid = blockIdx.x * 256 + threadIdx.x;     // ((n*64+d)*16)+b
    float Z = 0.0f, A = 0.0f;
    #pragma unroll
    for (int ic = 0; ic < IC; ++ic) {
        const float* p = part2 + ((size_t)ic * BND + gid) * 2;
        Z += p[0];
        A += p[1];
    }
    const int b = gid & 15, d = (gid >> 4) & 63, n = gid >> 10;
    const int ci = (b * N_ + n) * D_ + d;
    float o = squash1(A / Z);
    outp[ci] = final_ ? o : (coefIn[ci] + o);
}

extern "C" void kernel_launch(void* const* d_in, const int* in_sizes, int n_in,
                              void* d_out, int out_size, void* d_ws, size_t ws_size,
                              hipStream_t stream) {
    const float* inp = (const float*)d_in[0];
    const float* W   = (const float*)d_in[1];
    float* out = (float*)d_out;

    unsigned short* xh2 = (unsigned short*)d_ws;                    // 75,497,472 B
    float* part  = (float*)((char*)d_ws + 75497472);                // 18,874,368 B
    float* part2 = (float*)((char*)d_ws + 94371840);                //  4,194,304 B
    float* coef  = (float*)((char*)d_ws + 98566144);                //    131,072 B

    k_xhat<<<dim3(N_ * IB), dim3(256), 0, stream>>>(inp, W, xh2, part);
    k_out0<<<dim3(BND / 256), dim3(256), 0, stream>>>(part, coef);
    k_rpart<<<dim3(N_ * IC), dim3(256), 0, stream>>>(xh2, coef, part2);
    k_rfin <<<dim3(BND / 256), dim3(256), 0, stream>>>(part2, coef, coef, 0);
    k_rpart<<<dim3(N_ * IC), dim3(256), 0, stream>>>(xh2, coef, part2);
    k_rfin <<<dim3(BND / 256), dim3(256), 0, stream>>>(part2, coef, out, 1);
}

// Round 8
// 83.646 us; speedup vs baseline: 1.4663x; 1.4663x over previous
//
#include <hip/hip_runtime.h>
#include <hip/hip_bf16.h>
#include <math.h>

#define B_   16
#define N_   32
#define I_   1152
#define DIN  16
#define D_   64
#define TI   8             // i's per k_xhat block
#define IB   (I_/TI)       // 144 i-tiles
#define IC   16            // i-chunks in routing (72 i each)
#define BND  (B_*N_*D_)    // 32768

#if __has_builtin(__builtin_amdgcn_exp2f)
#define EXP2(x) __builtin_amdgcn_exp2f(x)
#else
#define EXP2(x) exp2f(x)
#endif

#define LOG2E 1.4426950408889634f

typedef __attribute__((ext_vector_type(8))) short short8v;
typedef __attribute__((ext_vector_type(4))) float f32x4;
typedef __attribute__((ext_vector_type(4))) unsigned int u32x4;
typedef __attribute__((ext_vector_type(2))) unsigned int u32x2;

__device__ __forceinline__ float squash1(float s) {
    float sq = s * s;
    return (sq / (1.0f + sq)) * s * rsqrtf(sq + 1e-9f);
}
__device__ __forceinline__ unsigned short bfh(float v) {
    return __builtin_bit_cast(unsigned short, __float2bfloat16(v));
}
__device__ __forceinline__ float bff(unsigned short u) {
    unsigned int x = ((unsigned int)u) << 16;
    return __builtin_bit_cast(float, x);
}

// K1: x_hat via MFMA, deep-pipelined W stream.
// - ALL 8 i-tiles of W are loaded via explicit dwordx4 in two 4-i groups
//   issued before any consumption (~16KB in flight per wave) to attack the
//   load-latency serialization that kept R1-R7 at ~90us (VGPR was 36-40 =>
//   only ~1-2KB in flight per wave).
// - inputs converted to bf16 ONCE into a 4KB XOR-swizzled LDS tile; per-i
//   B-fragment = one conflict-free ds_read_b128 (no per-i cvt, no scatter).
// - hi/lo W-residual trick: K-slots 0..15 = W_hi, 16..31 = W_lo, inputs
//   duplicated -> fp32-grade W precision in one MFMA.
// - xh2 layout [n][i][b][d] (bf16): lane's 4 C-values contiguous -> dwordx2.
// C-frag: col=lane&15=b, row(d)=mt*16+(lane>>4)*4+reg.
__global__ __launch_bounds__(256, 4) void k_xhat(const float* __restrict__ inp,
                                                 const float* __restrict__ W,
                                                 unsigned short* __restrict__ xh2,
                                                 float* __restrict__ part) {
    __shared__ __align__(16) unsigned short xs[2048];   // bf16 inp tile, swizzled
    const int bx = blockIdx.x;
    const int n  = bx / IB;
    const int ib = bx % IB;
    const int i0 = ib * TI;
    const int t  = threadIdx.x;
    const int l  = t & 63;
    const int mt = t >> 6;                 // wave id = d m-tile (0..3)
    const int row = l & 15;
    const int ko  = (l >> 4) & 1;          // k-octet for A/B frags

    // ---- stage inputs -> bf16 LDS tile, layout [b][il][koct][8], XOR-swizzled
    {
        const int sb  = t >> 4;            // batch 0..15
        const int sil = (t >> 1) & 7;      // i-local 0..7
        const int sko = t & 1;             // k-octet
        const float* src = inp + (size_t)sb * (I_ * DIN) + (size_t)(i0 + sil) * DIN + sko * 8;
        f32x4 a0 = *(const f32x4*)src;
        f32x4 a1 = *(const f32x4*)(src + 4);
        u32x4 p;
        p.x = ((unsigned)bfh(a0.y) << 16) | bfh(a0.x);
        p.y = ((unsigned)bfh(a0.w) << 16) | bfh(a0.z);
        p.z = ((unsigned)bfh(a1.y) << 16) | bfh(a1.x);
        p.w = ((unsigned)bfh(a1.w) << 16) | bfh(a1.z);
        int base = (sb * 256 + sil * 32 + sko * 16) ^ ((sb & 7) << 4);
        *(u32x4*)((char*)xs + base) = p;
    }
    __syncthreads();

    // ---- issue ALL W loads (two 4-i groups, 8 dwordx4 each)
    const float* wb = W + ((size_t)(n * I_ + i0) * 64 + mt * 16 + row) * 16 + ko * 8;
    f32x4 wv[16];
    #pragma unroll
    for (int i = 0; i < 4; ++i) {
        const f32x4* p = (const f32x4*)(wb + (size_t)i * 1024);
        wv[2 * i] = p[0]; wv[2 * i + 1] = p[1];
    }
    #pragma unroll
    for (int i = 4; i < 8; ++i) {
        const f32x4* p = (const f32x4*)(wb + (size_t)i * 1024);
        wv[2 * i] = p[0]; wv[2 * i + 1] = p[1];
    }

    f32x4 acc[TI];
    #pragma unroll
    for (int i = 0; i < TI; ++i) acc[i] = (f32x4){0.f, 0.f, 0.f, 0.f};

    const bool loHalf = (l >= 32);
    #pragma unroll
    for (int i = 0; i < TI; ++i) {
        // B-frag: one swizzled ds_read_b128 (8 bf16 of inp for col b=l&15)
        int xaddr = ((l & 15) * 256 + i * 32 + ko * 16) ^ (((l & 15) & 7) << 4);
        short8v bfrag = *(const short8v*)((const char*)xs + xaddr);
        // A-frag: convert W hi/lo
        short8v afrag;
        #pragma unroll
        for (int j = 0; j < 8; ++j) {
            float w = wv[2 * i + (j >> 2)][j & 3];
            unsigned short hi = bfh(w);
            unsigned short lo = bfh(w - bff(hi));
            afrag[j] = (short)(loHalf ? lo : hi);
        }
        acc[i] = __builtin_amdgcn_mfma_f32_16x16x32_bf16(afrag, bfrag, acc[i], 0, 0, 0);
    }

    // ---- s0 partials first (register-only), then fire-and-forget xh stores
    f32x4 s0v = acc[0];
    #pragma unroll
    for (int i = 1; i < TI; ++i) s0v += acc[i];
    size_t pidx = (((size_t)ib * B_ + (l & 15)) * N_ + n) * 64 + mt * 16 + (l >> 4) * 4;
    *(f32x4*)(part + pidx) = s0v;

    #pragma unroll
    for (int i = 0; i < TI; ++i) {
        u32x2 v;
        v.x = ((unsigned)bfh(acc[i][1]) << 16) | bfh(acc[i][0]);
        v.y = ((unsigned)bfh(acc[i][3]) << 16) | bfh(acc[i][2]);
        size_t off = (size_t)(n * I_ + i0 + i) * 1024 + (l & 15) * 64 + mt * 16 + (l >> 4) * 4;
        *reinterpret_cast<u32x2*>(xh2 + off) = v;
    }
}

// K2: coef = squash(mean over i of x_hat) — routing iteration 0.
// part layout [ib][b][n][d]; t packs (b,n,d) = coef index.
__global__ __launch_bounds__(256) void k_out0(const float* __restrict__ part,
                                              float* __restrict__ coef) {
    const int t = blockIdx.x * 256 + threadIdx.x;
    float s = 0.0f;
    for (int j = 0; j < IB; ++j) s += part[(size_t)j * BND + t];
    s *= (1.0f / (float)I_);
    coef[t] = squash1(s);
}

// K3: routing partial pass over xh2[n][i][b][d]. |logit| <= ~50 -> exp2 safe
// without max-tracking. Thread owns (b, d0..d0+3): one contiguous 8B read
// per i. part2 layout [ic][n][b][d][2] = {z,a}.
__global__ __launch_bounds__(256) void k_rpart(const unsigned short* __restrict__ xh2,
                                               const float* __restrict__ coef,
                                               float* __restrict__ part2) {
    const int bx = blockIdx.x;
    const int n  = bx >> 4;
    const int ic = bx & 15;
    const int t  = threadIdx.x;
    const int b  = t >> 4;
    const int dq = (t & 15) * 4;

    const unsigned short* base = xh2 + ((size_t)n * I_ + (size_t)ic * (I_ / IC)) * 1024
                               + b * 64 + dq;
    f32x4 c4 = *(const f32x4*)(coef + ((size_t)b * N_ + n) * 64 + dq);
    float c2[4] = {c4.x * LOG2E, c4.y * LOG2E, c4.z * LOG2E, c4.w * LOG2E};
    float z[4] = {0, 0, 0, 0}, a[4] = {0, 0, 0, 0};

    #pragma unroll 8
    for (int i = 0; i < I_ / IC; ++i) {
        u32x2 u = *(const u32x2*)(base + (size_t)i * 1024);
        unsigned short s4[4] = {(unsigned short)(u.x & 0xffffu), (unsigned short)(u.x >> 16),
                                (unsigned short)(u.y & 0xffffu), (unsigned short)(u.y >> 16)};
        #pragma unroll
        for (int j = 0; j < 4; ++j) {
            float x = bff(s4[j]);
            float e = EXP2(x * c2[j]);
            z[j] += e;
            a[j] = fmaf(e, x, a[j]);
        }
    }

    size_t pidx = ((((size_t)ic * N_ + n) * 16 + b) * 64 + dq) * 2;
    f32x4 v0 = {z[0], a[0], z[1], a[1]};
    f32x4 v1 = {z[2], a[2], z[3], a[3]};
    *(f32x4*)(part2 + pidx)     = v0;
    *(f32x4*)(part2 + pidx + 4) = v1;
}

// K4: routing finisher. gid packs (n,b,d) matching part2 inner order.
// final=0: coef += squash(a/z). final=1: out[b][n][d] = squash(a/z).
__global__ __launch_bounds__(256) void k_rfin(const float* __restrict__ part2,
                                              const float* __restrict__ coefIn,
                                              float* __restrict__ outp,
                                              int final_) {
    const int gid = blockIdx.x * 256 + threadIdx.x;     // n*1024 + b*64 + d
    float Z = 0.0f, A = 0.0f;
    #pragma unroll
    for (int ic = 0; ic < IC; ++ic) {
        const float* p = part2 + ((size_t)ic * BND + gid) * 2;
        Z += p[0];
        A += p[1];
    }
    const int d = gid & 63, b = (gid >> 6) & 15, n = gid >> 10;
    const int ci = (b * N_ + n) * D_ + d;
    float o = squash1(A / Z);
    outp[ci] = final_ ? o : (coefIn[ci] + o);
}

extern "C" void kernel_launch(void* const* d_in, const int* in_sizes, int n_in,
                              void* d_out, int out_size, void* d_ws, size_t ws_size,
                              hipStream_t stream) {
    const float* inp = (const float*)d_in[0];
    const float* W   = (const float*)d_in[1];
    float* out = (float*)d_out;

    unsigned short* xh2 = (unsigned short*)d_ws;                    // 75,497,472 B
    float* part  = (float*)((char*)d_ws + 75497472);                // 18,874,368 B
    float* part2 = (float*)((char*)d_ws + 94371840);                //  4,194,304 B
    float* coef  = (float*)((char*)d_ws + 98566144);                //    131,072 B

    k_xhat<<<dim3(N_ * IB), dim3(256), 0, stream>>>(inp, W, xh2, part);
    k_out0<<<dim3(BND / 256), dim3(256), 0, stream>>>(part, coef);
    k_rpart<<<dim3(N_ * IC), dim3(256), 0, stream>>>(xh2, coef, part2);
    k_rfin <<<dim3(BND / 256), dim3(256), 0, stream>>>(part2, coef, coef, 0);
    k_rpart<<<dim3(N_ * IC), dim3(256), 0, stream>>>(xh2, coef, part2);
    k_rfin <<<dim3(BND / 256), dim3(256), 0, stream>>>(part2, coef, out, 1);
}

// Round 9
// 80.870 us; speedup vs baseline: 1.5166x; 1.0343x over previous
//
#include <hip/hip_runtime.h>
#include <hip/hip_bf16.h>
#include <math.h>

#define B_   16
#define N_   32
#define I_   1152
#define DIN  16
#define D_   64
#define TI   8             // i's per k_xhat block
#define IB   (I_/TI)       // 144 i-tiles
#define IC   16            // i-chunks in routing (72 i each)
#define BND  (B_*N_*D_)    // 32768

#if __has_builtin(__builtin_amdgcn_exp2f)
#define EXP2(x) __builtin_amdgcn_exp2f(x)
#else
#define EXP2(x) exp2f(x)
#endif

#define LOG2E 1.4426950408889634f

typedef __attribute__((ext_vector_type(8))) short short8v;
typedef __attribute__((ext_vector_type(4))) float f32x4;
typedef __attribute__((ext_vector_type(4))) unsigned int u32x4;
typedef __attribute__((ext_vector_type(2))) unsigned int u32x2;

__device__ __forceinline__ float squash1(float s) {
    float sq = s * s;
    return (sq / (1.0f + sq)) * s * rsqrtf(sq + 1e-9f);
}
__device__ __forceinline__ unsigned short bfh(float v) {
    return __builtin_bit_cast(unsigned short, __float2bfloat16(v));
}
__device__ __forceinline__ float bff(unsigned short u) {
    unsigned int x = ((unsigned int)u) << 16;
    return __builtin_bit_cast(float, x);
}

// K1: x_hat via MFMA, deep W pipeline (R8) + LANE-ORDER xh2 layout so the
// store stream is fully coalesced (wave writes 512B contiguous per i vs
// R8's 64x8B scatter over 2KB => L2 half-line RMW).
// xh2 tile layout per (n,i): [mt][dgrp][b][4d]  (element off = 4*lane + mt*256)
//   where the C-frag gives lane l -> (b=l&15, d=mt*16+(l>>4)*4+r).
// hi/lo W-residual trick: K-slots 0..15 = W_hi, 16..31 = W_lo (inputs
// duplicated) -> fp32-grade W precision in one mfma_f32_16x16x32_bf16.
__global__ __launch_bounds__(256, 4) void k_xhat(const float* __restrict__ inp,
                                                 const float* __restrict__ W,
                                                 unsigned short* __restrict__ xh2,
                                                 float* __restrict__ part) {
    __shared__ __align__(16) unsigned short xs[2048];   // bf16 inp tile, swizzled
    const int bx = blockIdx.x;
    const int n  = bx / IB;
    const int ib = bx % IB;
    const int i0 = ib * TI;
    const int t  = threadIdx.x;
    const int l  = t & 63;
    const int mt = t >> 6;                 // wave id = d m-tile (0..3)
    const int row = l & 15;
    const int ko  = (l >> 4) & 1;          // k-octet for A/B frags

    // ---- stage inputs -> bf16 LDS tile, layout [b][il][koct][8], XOR-swizzled
    {
        const int sb  = t >> 4;            // batch 0..15
        const int sil = (t >> 1) & 7;      // i-local 0..7
        const int sko = t & 1;             // k-octet
        const float* src = inp + (size_t)sb * (I_ * DIN) + (size_t)(i0 + sil) * DIN + sko * 8;
        f32x4 a0 = *(const f32x4*)src;
        f32x4 a1 = *(const f32x4*)(src + 4);
        u32x4 p;
        p.x = ((unsigned)bfh(a0.y) << 16) | bfh(a0.x);
        p.y = ((unsigned)bfh(a0.w) << 16) | bfh(a0.z);
        p.z = ((unsigned)bfh(a1.y) << 16) | bfh(a1.x);
        p.w = ((unsigned)bfh(a1.w) << 16) | bfh(a1.z);
        int base = (sb * 256 + sil * 32 + sko * 16) ^ ((sb & 7) << 4);
        *(u32x4*)((char*)xs + base) = p;
    }
    __syncthreads();

    // ---- issue ALL W loads (16 dwordx4 per thread, ~16KB/wave in flight)
    const float* wb = W + ((size_t)(n * I_ + i0) * 64 + mt * 16 + row) * 16 + ko * 8;
    f32x4 wv[16];
    #pragma unroll
    for (int i = 0; i < 8; ++i) {
        const f32x4* p = (const f32x4*)(wb + (size_t)i * 1024);
        wv[2 * i] = p[0]; wv[2 * i + 1] = p[1];
    }

    f32x4 acc[TI];
    #pragma unroll
    for (int i = 0; i < TI; ++i) acc[i] = (f32x4){0.f, 0.f, 0.f, 0.f};

    const bool loHalf = (l >= 32);
    #pragma unroll
    for (int i = 0; i < TI; ++i) {
        int xaddr = ((l & 15) * 256 + i * 32 + ko * 16) ^ (((l & 15) & 7) << 4);
        short8v bfrag = *(const short8v*)((const char*)xs + xaddr);
        short8v afrag;
        #pragma unroll
        for (int j = 0; j < 8; ++j) {
            float w = wv[2 * i + (j >> 2)][j & 3];
            unsigned short hi = bfh(w);
            unsigned short lo = bfh(w - bff(hi));
            afrag[j] = (short)(loHalf ? lo : hi);
        }
        acc[i] = __builtin_amdgcn_mfma_f32_16x16x32_bf16(afrag, bfrag, acc[i], 0, 0, 0);
    }

    // ---- s0 partials (register-only), then fully-coalesced xh stores
    f32x4 s0v = acc[0];
    #pragma unroll
    for (int i = 1; i < TI; ++i) s0v += acc[i];
    size_t pidx = (((size_t)ib * B_ + (l & 15)) * N_ + n) * 64 + mt * 16 + (l >> 4) * 4;
    *(f32x4*)(part + pidx) = s0v;

    #pragma unroll
    for (int i = 0; i < TI; ++i) {
        u32x2 v;
        v.x = ((unsigned)bfh(acc[i][1]) << 16) | bfh(acc[i][0]);
        v.y = ((unsigned)bfh(acc[i][3]) << 16) | bfh(acc[i][2]);
        size_t off = (size_t)(n * I_ + i0 + i) * 1024 + (size_t)t * 4;  // mt*256 + 4*l
        *reinterpret_cast<u32x2*>(xh2 + off) = v;
    }
}

// K2: coef = squash(mean over i of x_hat) — routing iteration 0.
// part layout [ib][b][n][d]; t packs (b,n,d) = coef index.
__global__ __launch_bounds__(256) void k_out0(const float* __restrict__ part,
                                              float* __restrict__ coef) {
    const int t = blockIdx.x * 256 + threadIdx.x;
    float s = 0.0f;
    for (int j = 0; j < IB; ++j) s += part[(size_t)j * BND + t];
    s *= (1.0f / (float)I_);
    coef[t] = squash1(s);
}

// K3: routing partial pass. xh2 tile layout [mt][dgrp][b][4d]: thread t owns
// exactly element-offset 4t per i-tile => wave reads 512B CONTIGUOUS per i.
// Thread's logical coords: b = t&15, d0 = (t>>4)*4. |logit|<=~50 -> exp2
// safe without max-tracking. part2 layout [ic][n][b][d][2] = {z,a}.
__global__ __launch_bounds__(256) void k_rpart(const unsigned short* __restrict__ xh2,
                                               const float* __restrict__ coef,
                                               float* __restrict__ part2) {
    const int bx = blockIdx.x;
    const int n  = bx >> 4;
    const int ic = bx & 15;
    const int t  = threadIdx.x;
    const int b  = t & 15;
    const int d0 = (t >> 4) * 4;

    const unsigned short* base = xh2 + ((size_t)n * I_ + (size_t)ic * (I_ / IC)) * 1024
                               + (size_t)t * 4;
    f32x4 c4 = *(const f32x4*)(coef + ((size_t)b * N_ + n) * 64 + d0);
    float c2[4] = {c4.x * LOG2E, c4.y * LOG2E, c4.z * LOG2E, c4.w * LOG2E};
    float z[4] = {0, 0, 0, 0}, a[4] = {0, 0, 0, 0};

    #pragma unroll 8
    for (int i = 0; i < I_ / IC; ++i) {
        u32x2 u = *(const u32x2*)(base + (size_t)i * 1024);
        unsigned short s4[4] = {(unsigned short)(u.x & 0xffffu), (unsigned short)(u.x >> 16),
                                (unsigned short)(u.y & 0xffffu), (unsigned short)(u.y >> 16)};
        #pragma unroll
        for (int j = 0; j < 4; ++j) {
            float x = bff(s4[j]);
            float e = EXP2(x * c2[j]);
            z[j] += e;
            a[j] = fmaf(e, x, a[j]);
        }
    }

    size_t pidx = ((((size_t)ic * N_ + n) * 16 + b) * 64 + d0) * 2;
    f32x4 v0 = {z[0], a[0], z[1], a[1]};
    f32x4 v1 = {z[2], a[2], z[3], a[3]};
    *(f32x4*)(part2 + pidx)     = v0;
    *(f32x4*)(part2 + pidx + 4) = v1;
}

// K4: routing finisher. gid packs (n,b,d) matching part2 inner order.
// final=0: coef += squash(a/z). final=1: out[b][n][d] = squash(a/z).
__global__ __launch_bounds__(256) void k_rfin(const float* __restrict__ part2,
                                              const float* __restrict__ coefIn,
                                              float* __restrict__ outp,
                                              int final_) {
    const int gid = blockIdx.x * 256 + threadIdx.x;     // n*1024 + b*64 + d
    float Z = 0.0f, A = 0.0f;
    #pragma unroll
    for (int ic = 0; ic < IC; ++ic) {
        const float* p = part2 + ((size_t)ic * BND + gid) * 2;
        Z += p[0];
        A += p[1];
    }
    const int d = gid & 63, b = (gid >> 6) & 15, n = gid >> 10;
    const int ci = (b * N_ + n) * D_ + d;
    float o = squash1(A / Z);
    outp[ci] = final_ ? o : (coefIn[ci] + o);
}

extern "C" void kernel_launch(void* const* d_in, const int* in_sizes, int n_in,
                              void* d_out, int out_size, void* d_ws, size_t ws_size,
                              hipStream_t stream) {
    const float* inp = (const float*)d_in[0];
    const float* W   = (const float*)d_in[1];
    float* out = (float*)d_out;

    unsigned short* xh2 = (unsigned short*)d_ws;                    // 75,497,472 B
    float* part  = (float*)((char*)d_ws + 75497472);                // 18,874,368 B
    float* part2 = (float*)((char*)d_ws + 94371840);                //  4,194,304 B
    float* coef  = (float*)((char*)d_ws + 98566144);                //    131,072 B

    k_xhat<<<dim3(N_ * IB), dim3(256), 0, stream>>>(inp, W, xh2, part);
    k_out0<<<dim3(BND / 256), dim3(256), 0, stream>>>(part, coef);
    k_rpart<<<dim3(N_ * IC), dim3(256), 0, stream>>>(xh2, coef, part2);
    k_rfin <<<dim3(BND / 256), dim3(256), 0, stream>>>(part2, coef, coef, 0);
    k_rpart<<<dim3(N_ * IC), dim3(256), 0, stream>>>(xh2, coef, part2);
    k_rfin <<<dim3(BND / 256), dim3(256), 0, stream>>>(part2, coef, out, 1);
}